// Round 2
// baseline (320.959 us; speedup 1.0000x reference)
//
#include <hip/hip_runtime.h>

// Problem: B=16, C=128, K=128, D=256. Inputs f32, outputs FLOAT32.
// d_out (float): out0 (B,C,D) @ 0, out1 (B,C,K,D) @ 524288, out2 (B,C,K) @ 67633152.

#define NB 16
#define NC 128
#define NK 128
#define ND 256

// ---------------- Kernel 1: dual SGEMM  Y[m,d] = sum_j A[m,j]*W[d,j] ----------------
// M = 4096 (rows 0..2047 = q with W0, rows 2048..4095 = kc with W1), K=256, N=256.
// 64x64 tile per block, 256 threads, 4x4 microtile, K-chunk 16.
__global__ __launch_bounds__(256) void k_gemm(const float* __restrict__ q,
                                              const float* __restrict__ kc,
                                              const float* __restrict__ W0,
                                              const float* __restrict__ W1,
                                              float* __restrict__ Y) {
    __shared__ float As[16][64];
    __shared__ float Bs[16][64];
    const int m0 = blockIdx.x * 64;
    const int d0 = blockIdx.y * 64;
    const int t  = threadIdx.x;
    const float* A = (m0 < 2048) ? (q + (size_t)m0 * ND) : (kc + (size_t)(m0 - 2048) * ND);
    const float* W = (m0 < 2048) ? W0 : W1;
    const int ml = t >> 2;          // 0..63 (row within tile for loads)
    const int jl = (t & 3) * 4;     // 0,4,8,12 (k within chunk)
    const int ty = t >> 4;          // 0..15 -> m sub-tile
    const int tx = t & 15;          // 0..15 -> n sub-tile

    float acc[4][4] = {};
    for (int j0 = 0; j0 < 256; j0 += 16) {
        float4 a = *(const float4*)(A + ml * ND + j0 + jl);
        float4 b = *(const float4*)(W + (d0 + ml) * ND + j0 + jl);
        As[jl + 0][ml] = a.x; As[jl + 1][ml] = a.y; As[jl + 2][ml] = a.z; As[jl + 3][ml] = a.w;
        Bs[jl + 0][ml] = b.x; Bs[jl + 1][ml] = b.y; Bs[jl + 2][ml] = b.z; Bs[jl + 3][ml] = b.w;
        __syncthreads();
#pragma unroll
        for (int jj = 0; jj < 16; ++jj) {
            float4 av = *(const float4*)&As[jj][ty * 4];
            float4 bv = *(const float4*)&Bs[jj][tx * 4];
            acc[0][0] += av.x * bv.x; acc[0][1] += av.x * bv.y; acc[0][2] += av.x * bv.z; acc[0][3] += av.x * bv.w;
            acc[1][0] += av.y * bv.x; acc[1][1] += av.y * bv.y; acc[1][2] += av.y * bv.z; acc[1][3] += av.y * bv.w;
            acc[2][0] += av.z * bv.x; acc[2][1] += av.z * bv.y; acc[2][2] += av.z * bv.z; acc[2][3] += av.z * bv.w;
            acc[3][0] += av.w * bv.x; acc[3][1] += av.w * bv.y; acc[3][2] += av.w * bv.z; acc[3][3] += av.w * bv.w;
        }
        __syncthreads();
    }
#pragma unroll
    for (int i = 0; i < 4; ++i) {
        float4 o = make_float4(acc[i][0], acc[i][1], acc[i][2], acc[i][3]);
        *(float4*)(Y + (size_t)(m0 + ty * 4 + i) * ND + d0 + tx * 4) = o;
    }
}

// ---------------- Kernel 2: BN stats per channel (256 channels: 0..127 bn0, 128..255 bn1) ----
__global__ __launch_bounds__(256) void k_stats(const float* __restrict__ Y,
                                               const float* __restrict__ g0, const float* __restrict__ b0,
                                               const float* __restrict__ g1, const float* __restrict__ b1,
                                               float* __restrict__ sc, float* __restrict__ sh) {
    const int ch = blockIdx.x;
    const int t  = threadIdx.x;
    const int rbase = (ch < 128) ? ch : (2048 + (ch - 128));
    float s = 0.f, s2 = 0.f;
#pragma unroll
    for (int b = 0; b < NB; ++b) {
        float v = Y[(size_t)(rbase + b * 128) * ND + t];
        s += v; s2 += v * v;
    }
#pragma unroll
    for (int off = 32; off > 0; off >>= 1) {
        s  += __shfl_down(s,  off, 64);
        s2 += __shfl_down(s2, off, 64);
    }
    __shared__ float r1[4], r2[4];
    const int w = t >> 6;
    if ((t & 63) == 0) { r1[w] = s; r2[w] = s2; }
    __syncthreads();
    if (t == 0) {
        s  = r1[0] + r1[1] + r1[2] + r1[3];
        s2 = r2[0] + r2[1] + r2[2] + r2[3];
        float mean = s * (1.f / 4096.f);
        float var  = s2 * (1.f / 4096.f) - mean * mean;   // biased, matches torch/jnp
        float rstd = rsqrtf(var + 1e-5f);
        float g  = (ch < 128) ? g0[ch] : g1[ch - 128];
        float be = (ch < 128) ? b0[ch] : b1[ch - 128];
        sc[ch] = g * rstd;
        sh[ch] = be - mean * g * rstd;
    }
}

// ---------------- Kernel 3: in-place sigmoid(BN(Y)) ----------------
__global__ __launch_bounds__(256) void k_apply(float* __restrict__ Y,
                                               const float* __restrict__ sc, const float* __restrict__ sh) {
    const int m = blockIdx.x;          // 0..4095
    const int t = threadIdx.x;
    const size_t idx = (size_t)m * ND + t;
    float x = Y[idx];
    const int ch = (m < 2048) ? (m & 127) : (128 + (m & 127));
    float g = x * sc[ch] + sh[ch];
    Y[idx] = 1.f / (1.f + __expf(-g));
}

// ---------------- Kernel 4: big write + out2 dot + t-accumulate + out0 ----------------
// One block per (b,c). 256 threads: f = t&63 covers d via float4 (64*4=256), g = t>>6 covers k phase.
__global__ __launch_bounds__(256) void k_big(const float* __restrict__ Y,   // s0 rows [0,2048), s1 rows [2048,4096)
                                             const float* __restrict__ kc,
                                             const int* __restrict__ cmask,
                                             const int* __restrict__ kmask,
                                             const int* __restrict__ klen,
                                             float* __restrict__ out0,
                                             float* __restrict__ out1,
                                             float* __restrict__ out2) {
    const int bc = blockIdx.x;     // b*128 + c
    const int b  = bc >> 7;
    const int t  = threadIdx.x;
    const int f  = t & 63;
    const int g  = t >> 6;

    const float* s0row = Y + (size_t)bc * ND;
    const float* s1b   = Y + (size_t)(2048 + b * 128) * ND;
    const float* kcb   = kc + (size_t)b * 128 * ND;
    const int*   kmb   = kmask + b * 128;

    float4 s0v = *(const float4*)(s0row + f * 4);            // unmasked sigmoid (for out2)
    const bool cm = cmask[bc] != 0;
    float4 v0 = cm ? s0v : make_float4(0.f, 0.f, 0.f, 0.f);  // cmask-applied

    float tx_ = 0.f, ty_ = 0.f, tz_ = 0.f, tw_ = 0.f;        // t[b,d] partial over this thread's k's
    const size_t o1base = (size_t)bc * 128 * ND;

    for (int k0 = 0; k0 < 32; ++k0) {
        const int k = k0 * 4 + g;
        float4 s1v = *(const float4*)(s1b + (size_t)k * ND + f * 4);
        float4 kcv = *(const float4*)(kcb + (size_t)k * ND + f * 4);
        const float km = (float)kmb[k];

        // u = kmask * kc * s1
        float4 uv = make_float4(km * kcv.x * s1v.x, km * kcv.y * s1v.y,
                                km * kcv.z * s1v.z, km * kcv.w * s1v.w);

        // out1 = (cmask*s0) * u
        *(float4*)(out1 + o1base + (size_t)k * ND + f * 4) =
            make_float4(v0.x * uv.x, v0.y * uv.y, v0.z * uv.z, v0.w * uv.w);

        tx_ += uv.x; ty_ += uv.y; tz_ += uv.z; tw_ += uv.w;

        // out2 = mean_d s0*s1 (unmasked)
        float dot = s0v.x * s1v.x + s0v.y * s1v.y + s0v.z * s1v.z + s0v.w * s1v.w;
#pragma unroll
        for (int off = 32; off > 0; off >>= 1) dot += __shfl_down(dot, off, 64);
        if (f == 0) out2[(size_t)bc * 128 + k] = dot * (1.f / 256.f);
    }

    __shared__ float tl[4][256];
    *(float4*)&tl[g][f * 4] = make_float4(tx_, ty_, tz_, tw_);
    __syncthreads();
    if (g == 0) {
        float4 t0 = *(const float4*)&tl[0][f * 4];
        float4 t1 = *(const float4*)&tl[1][f * 4];
        float4 t2 = *(const float4*)&tl[2][f * 4];
        float4 t3 = *(const float4*)&tl[3][f * 4];
        const float inv = 1.f / (float)klen[b];
        float ax = tanhf(v0.x * (t0.x + t1.x + t2.x + t3.x) * inv);
        float ay = tanhf(v0.y * (t0.y + t1.y + t2.y + t3.y) * inv);
        float az = tanhf(v0.z * (t0.z + t1.z + t2.z + t3.z) * inv);
        float aw = tanhf(v0.w * (t0.w + t1.w + t2.w + t3.w) * inv);
        *(float4*)(out0 + (size_t)bc * ND + f * 4) = make_float4(ax, ay, az, aw);
    }
}

extern "C" void kernel_launch(void* const* d_in, const int* in_sizes, int n_in,
                              void* d_out, int out_size, void* d_ws, size_t ws_size,
                              hipStream_t stream) {
    const float* q     = (const float*)d_in[0];
    const float* kc    = (const float*)d_in[1];
    const float* W0    = (const float*)d_in[2];
    const float* W1    = (const float*)d_in[3];
    const float* g0    = (const float*)d_in[4];
    const float* b0    = (const float*)d_in[5];
    const float* g1    = (const float*)d_in[6];
    const float* b1    = (const float*)d_in[7];
    const int*   cmask = (const int*)d_in[8];
    const int*   kmask = (const int*)d_in[9];
    const int*   klen  = (const int*)d_in[10];

    float* ws = (float*)d_ws;
    float* Y  = ws;                 // 4096*256 = 1048576 f32 (sigmoid(BN(.)) in place after k_apply)
    float* sc = ws + 1048576;       // 256
    float* sh = ws + 1048832;       // 256

    float* o    = (float*)d_out;
    float* out0 = o;                 // 16*128*256      = 524288
    float* out1 = o + 524288;        // 16*128*128*256  = 67108864
    float* out2 = o + 67633152;      // 16*128*128      = 262144

    k_gemm<<<dim3(64, 4), 256, 0, stream>>>(q, kc, W0, W1, Y);
    k_stats<<<256, 256, 0, stream>>>(Y, g0, b0, g1, b1, sc, sh);
    k_apply<<<4096, 256, 0, stream>>>(Y, sc, sh);
    k_big<<<2048, 256, 0, stream>>>(Y, kc, cmask, kmask, klen, out0, out1, out2);
}